// Round 15
// baseline (645.574 us; speedup 1.0000x reference)
//
#include <hip/hip_runtime.h>

// Swin window attention, persistent fused MFMA pipeline. Grid 1024; each block
// (6 waves) processes 4 windows {b, b+1024, b+2048, b+3072} -- all sharing ONE
// mask row. Wave w owns head w. B=4096, N=64, C=180, H=6, D=30 (pad 32).
//
// Round-15 = round-13 phase code (285.9 us) + persistent window loop:
//   - 4 windows/block at stride 1024: mask row identical -> L1/L2-hot for
//     windows 2-4, mask HBM traffic /4.
//   - next window's x staged UNDER the proj phase (loads at proj start, cvt+
//     LDS-write after; +32 regs only in the ~70-reg proj phase -> no spill),
//     double-buffered LDS (2 x 25.6 KB). Loop-end barrier replaces phase-1's.
//   - pad cols zeroed ONCE for both buffers at start.
//   r14's (384,5) cap spilled (FETCH 142/WRITE 216 MB) -- stay at (384,4).
//
// d_ws (prep_w fills every launch):
//   [0)       wqkvT  bf16 [576][192]  oc = h*96 + sec*32 + d  (0=q,1=k,2=v)
//   [221184)  wprojT bf16 [192][192]  n-major
//   [294912)  relb   f32  [6][64][64] pre-gathered rel-pos bias
//
// Fragment-permutation trick (verified r2-r14): MFMA contracts A-slot(g,s)
// with B-slot(g,s); q/k fragments carry d(g,s)=16*(s>=4)+4g+(s&3) and P/V
// fragments carry j(g,s,k2)=32k2+16*(s>=4)+4g+(s&3) -- identical bijections
// on both operands, so no cross-lane traffic anywhere.

typedef __bf16 bf16;
typedef bf16 bf16x8 __attribute__((ext_vector_type(8)));
typedef float f32x4 __attribute__((ext_vector_type(4)));

#define MFMA(a, b, c) __builtin_amdgcn_mfma_f32_16x16x32_bf16(a, b, c, 0, 0, 0)

__global__ void prep_w(const float* __restrict__ wqkv,
                       const float* __restrict__ wproj,
                       const float* __restrict__ btab,
                       bf16* __restrict__ wqkvT,
                       bf16* __restrict__ wprojT,
                       float* __restrict__ relb)
{
    const int idx = blockIdx.x * 256 + threadIdx.x;
    if (idx < 110592) {                          // wqkvT [576][192]
        const int oc = idx / 192, kk = idx - oc * 192;
        const int h = oc / 96, r = oc - h * 96;
        const int sec = r >> 5, d = r & 31;
        wqkvT[idx] = (bf16)((kk < 180 && d < 30) ? wqkv[kk * 540 + sec * 180 + h * 30 + d] : 0.f);
    } else if (idx < 147456) {                   // wprojT [192][192]
        const int r = idx - 110592;
        const int n = r / 192, k = r - n * 192;
        wprojT[r] = (bf16)((n < 180 && k < 180) ? wproj[k * 180 + n] : 0.f);
    } else if (idx < 172032) {                   // relb [6][64][64]
        const int r = idx - 147456;
        const int h = r >> 12;
        const int ij = r & 4095;
        const int i = ij >> 6, j = ij & 63;
        const int rel = ((i >> 3) - (j >> 3) + 7) * 15 + ((i & 7) - (j & 7) + 7);
        relb[r] = btab[rel * 6 + h];
    }
}

__device__ __forceinline__ unsigned pack2(float a, float b) {
    return (unsigned)__builtin_bit_cast(unsigned short, (bf16)a)
         | ((unsigned)__builtin_bit_cast(unsigned short, (bf16)b) << 16);
}

__global__ __launch_bounds__(384, 4)
void swin_mfma(const float* __restrict__ xg_all,
               const float* __restrict__ mask_all,
               const float* __restrict__ bproj,
               const bf16* __restrict__ wqkvT,
               const bf16* __restrict__ wprojT,
               const float* __restrict__ relb,
               float* __restrict__ outg)
{
    __shared__ __align__(16) short xb2[2][64 * 200];   // double buffer: x / z bf16

    const int b    = blockIdx.x;                 // base window; masks share row b
    const int tid  = threadIdx.x;
    const int w    = tid >> 6;                   // wave = head, 0..5
    const int lane = tid & 63;
    const int l15  = lane & 15;
    const int g    = lane >> 4;                  // 0..3

    const float* maskw = mask_all + (size_t)b * 4096;   // b < 1024: b & 1023 == b
    const bf16*  wqh   = wqkvT + (size_t)(w * 96) * 192;
    const int rowoff   = l15 * 192 + 8 * g;
    const float* relh  = relb + w * 4096;

    // ---- prologue: zero pad cols [180..200) of BOTH buffers (once); stage
    // window b into buf 0 (batched loads, single wait).
    for (int e = tid; e < 1280; e += 384) {
        const int bi = (e >= 640) ? 1 : 0;
        const int e2 = e - bi * 640;
        const int i = e2 / 10;
        ((unsigned*)(&xb2[bi][0] + i * 200 + 180))[e2 - i * 10] = 0u;
    }
    {
        const float* xg = xg_all + (size_t)b * 11520;
        float4 xv[7];
        #pragma unroll
        for (int u = 0; u < 7; u++)
            xv[u] = *reinterpret_cast<const float4*>(xg + 4 * (tid + 384 * u));
        float4 xt;
        if (tid < 192) xt = *reinterpret_cast<const float4*>(xg + 4 * (2688 + tid));
        #pragma unroll
        for (int u = 0; u < 7; u++) {
            const int e = tid + 384 * u;
            const int i = e / 45;
            const int c = 4 * e - i * 180;
            *reinterpret_cast<unsigned*>(&xb2[0][0] + i * 200 + c)     = pack2(xv[u].x, xv[u].y);
            *reinterpret_cast<unsigned*>(&xb2[0][0] + i * 200 + c + 2) = pack2(xv[u].z, xv[u].w);
        }
        if (tid < 192) {
            const int e = 2688 + tid;
            const int i = e / 45;
            const int c = 4 * e - i * 180;
            *reinterpret_cast<unsigned*>(&xb2[0][0] + i * 200 + c)     = pack2(xt.x, xt.y);
            *reinterpret_cast<unsigned*>(&xb2[0][0] + i * 200 + c + 2) = pack2(xt.z, xt.w);
        }
    }
    __syncthreads();

    int cur = 0;
    #pragma unroll 1
    for (int wi = 0; wi < 4; ++wi) {
        short* const xb = &xb2[cur][0];
        const int bw = b + 1024 * wi;

        // ---- phase 2qk: q,k (swapped mfma: lane=token, regs=channels)
        bf16x8 qf[4], kf[4];                     // slot s <-> d = 16*(s>=4)+4g+(s&3)
        {
            f32x4 aqk[4][4];                     // [ct][tt] ct: q0,q1,k0,k1
            #pragma unroll
            for (int ct = 0; ct < 4; ct++)
                #pragma unroll
                for (int tt = 0; tt < 4; tt++) aqk[ct][tt] = (f32x4)0.f;
            #pragma unroll
            for (int ks = 0; ks < 6; ks++) {
                bf16x8 xf[4];
                #pragma unroll
                for (int tt = 0; tt < 4; tt++)
                    xf[tt] = *reinterpret_cast<const bf16x8*>(xb + (16 * tt + l15) * 200 + 32 * ks + 8 * g);
                __builtin_amdgcn_s_setprio(1);
                #pragma unroll
                for (int ct = 0; ct < 4; ct++) {
                    const bf16x8 wf = *reinterpret_cast<const bf16x8*>(wqh + ct * 3072 + rowoff + 32 * ks);
                    #pragma unroll
                    for (int tt = 0; tt < 4; tt++)
                        aqk[ct][tt] = MFMA(wf, xf[tt], aqk[ct][tt]);
                }
                __builtin_amdgcn_s_setprio(0);
            }
            #pragma unroll
            for (int tt = 0; tt < 4; tt++)
                #pragma unroll
                for (int s = 0; s < 8; s++) {
                    qf[tt][s] = (bf16)(aqk[s >> 2][tt][s & 3] * 0.18257418583505537f);
                    kf[tt][s] = (bf16)(aqk[2 + (s >> 2)][tt][s & 3]);
                }
        }
        __builtin_amdgcn_sched_barrier(0);

        // ---- phase 3: QK^T + softmax. Combined rel+mask bias rides the MFMA
        // C-operand; no-max softmax (validated r12/r13); it+1 bias prefetched.
        bf16x8 pf[4][2];                         // [it][k2]
        {
            f32x4 bc[4];
            {
                const float* rbb = relh + l15 * 64 + 4 * g;
                const float* mkb = maskw + l15 * 64 + 4 * g;
                #pragma unroll
                for (int jt = 0; jt < 4; jt++) {
                    const float4 rb = *reinterpret_cast<const float4*>(rbb + 16 * jt);
                    const float4 mk = *reinterpret_cast<const float4*>(mkb + 16 * jt);
                    bc[jt][0] = rb.x + mk.x; bc[jt][1] = rb.y + mk.y;
                    bc[jt][2] = rb.z + mk.z; bc[jt][3] = rb.w + mk.w;
                }
            }
            #pragma unroll
            for (int it = 0; it < 4; it++) {
                f32x4 stj[4];                    // j = 16jt+4g+r, i = 16it+l15
                __builtin_amdgcn_s_setprio(1);
                #pragma unroll
                for (int jt = 0; jt < 4; jt++) stj[jt] = MFMA(kf[jt], qf[it], bc[jt]);
                __builtin_amdgcn_s_setprio(0);

                f32x4 bn[4];
                if (it < 3) {
                    const int i1 = 16 * (it + 1) + l15;
                    const float* rbb = relh + i1 * 64 + 4 * g;
                    const float* mkb = maskw + i1 * 64 + 4 * g;
                    #pragma unroll
                    for (int jt = 0; jt < 4; jt++) {
                        const float4 rb = *reinterpret_cast<const float4*>(rbb + 16 * jt);
                        const float4 mk = *reinterpret_cast<const float4*>(mkb + 16 * jt);
                        bn[jt][0] = rb.x + mk.x; bn[jt][1] = rb.y + mk.y;
                        bn[jt][2] = rb.z + mk.z; bn[jt][3] = rb.w + mk.w;
                    }
                }

                float sum = 0.f;                 // no-max: exp directly
                #pragma unroll
                for (int jt = 0; jt < 4; jt++) {
                    const float e0 = __expf(stj[jt][0]);
                    const float e1 = __expf(stj[jt][1]);
                    const float e2 = __expf(stj[jt][2]);
                    const float e3 = __expf(stj[jt][3]);
                    stj[jt][0] = e0; stj[jt][1] = e1; stj[jt][2] = e2; stj[jt][3] = e3;
                    sum += (e0 + e1) + (e2 + e3);
                }
                sum += __shfl_xor(sum, 16);
                sum += __shfl_xor(sum, 32);
                const float inv = 1.0f / sum;
                #pragma unroll
                for (int k2 = 0; k2 < 2; k2++)
                    #pragma unroll
                    for (int s = 0; s < 8; s++)
                        pf[it][k2][s] = (bf16)(stj[2 * k2 + (s >> 2)][s & 3] * inv);

                if (it < 3) {
                    #pragma unroll
                    for (int jt = 0; jt < 4; jt++) bc[jt] = bn[jt];
                }
            }
        }
        __builtin_amdgcn_sched_barrier(0);

        // ---- phase 2v (deferred): v (normal mfma: lane=channel, regs=tokens)
        bf16x8 vf[2][2];                         // [cv][k2]
        {
            f32x4 av[4][2];                      // [tt][cv]
            #pragma unroll
            for (int tt = 0; tt < 4; tt++) { av[tt][0] = (f32x4)0.f; av[tt][1] = (f32x4)0.f; }
            #pragma unroll
            for (int ks = 0; ks < 6; ks++) {
                bf16x8 xf[4];
                #pragma unroll
                for (int tt = 0; tt < 4; tt++)
                    xf[tt] = *reinterpret_cast<const bf16x8*>(xb + (16 * tt + l15) * 200 + 32 * ks + 8 * g);
                __builtin_amdgcn_s_setprio(1);
                #pragma unroll
                for (int cv = 0; cv < 2; cv++) {
                    const bf16x8 wf = *reinterpret_cast<const bf16x8*>(wqh + (4 + cv) * 3072 + rowoff + 32 * ks);
                    #pragma unroll
                    for (int tt = 0; tt < 4; tt++)
                        av[tt][cv] = MFMA(xf[tt], wf, av[tt][cv]);
                }
                __builtin_amdgcn_s_setprio(0);
            }
            #pragma unroll
            for (int cv = 0; cv < 2; cv++)
                #pragma unroll
                for (int k2 = 0; k2 < 2; k2++)
                    #pragma unroll
                    for (int s = 0; s < 8; s++)
                        vf[cv][k2][s] = (bf16)(av[2 * k2 + (s >> 2)][cv][s & 3]);
        }
        __builtin_amdgcn_sched_barrier(0);

        // ---- phase 4: PV, all in registers
        f32x4 zacc[4][2];                        // [it][cv]: z[16it+4g+r][16cv+l15]
        #pragma unroll
        for (int it = 0; it < 4; it++) { zacc[it][0] = (f32x4)0.f; zacc[it][1] = (f32x4)0.f; }
        __builtin_amdgcn_s_setprio(1);
        #pragma unroll
        for (int k2 = 0; k2 < 2; k2++)
            #pragma unroll
            for (int cv = 0; cv < 2; cv++)
                #pragma unroll
                for (int it = 0; it < 4; it++)
                    zacc[it][cv] = MFMA(pf[it][k2], vf[cv][k2], zacc[it][cv]);
        __builtin_amdgcn_s_setprio(0);

        __syncthreads();                         // all waves done reading xb
        // z -> xb (aliased; pad cols still zero from prologue)
        #pragma unroll
        for (int cv = 0; cv < 2; cv++) {
            const int d = 16 * cv + l15;
            if (d < 30) {
                #pragma unroll
                for (int it = 0; it < 4; it++)
                    #pragma unroll
                    for (int r = 0; r < 4; r++)
                        xb[(16 * it + 4 * g + r) * 200 + w * 30 + d] =
                            __builtin_bit_cast(short, (bf16)zacc[it][cv][r]);
            }
        }
        __syncthreads();

        // ---- phase 5: proj GEMM + bias -> out, with next window's x staged
        // underneath (loads issued first, LDS writes after the MFMAs).
        float4 nxv[7], nxt;
        if (wi < 3) {
            const float* xgn = xg_all + (size_t)(bw + 1024) * 11520;
            #pragma unroll
            for (int u = 0; u < 7; u++)
                nxv[u] = *reinterpret_cast<const float4*>(xgn + 4 * (tid + 384 * u));
            if (tid < 192) nxt = *reinterpret_cast<const float4*>(xgn + 4 * (2688 + tid));
        }

        f32x4 pa[4][2];
        #pragma unroll
        for (int mt = 0; mt < 4; mt++) { pa[mt][0] = (f32x4)0.f; pa[mt][1] = (f32x4)0.f; }
        #pragma unroll
        for (int ks = 0; ks < 6; ks++) {
            bf16x8 zf[4];
            #pragma unroll
            for (int mt = 0; mt < 4; mt++)
                zf[mt] = *reinterpret_cast<const bf16x8*>(xb + (16 * mt + l15) * 200 + 32 * ks + 8 * g);
            __builtin_amdgcn_s_setprio(1);
            #pragma unroll
            for (int q2 = 0; q2 < 2; q2++) {
                const bf16x8 wf = *reinterpret_cast<const bf16x8*>(
                    wprojT + ((2 * w + q2) * 16 + l15) * 192 + 32 * ks + 8 * g);
                #pragma unroll
                for (int mt = 0; mt < 4; mt++)
                    pa[mt][q2] = MFMA(zf[mt], wf, pa[mt][q2]);
            }
            __builtin_amdgcn_s_setprio(0);
        }
        #pragma unroll
        for (int q2 = 0; q2 < 2; q2++) {
            const int n = (2 * w + q2) * 16 + l15;
            if (n < 180) {
                const float bn = bproj[n];
                float* const ob = outg + (size_t)bw * 11520 + n;
                #pragma unroll
                for (int mt = 0; mt < 4; mt++)
                    #pragma unroll
                    for (int r = 0; r < 4; r++)
                        ob[(16 * mt + 4 * g + r) * 180] = pa[mt][q2][r] + bn;
            }
        }

        if (wi < 3) {                            // write staged x into other buffer
            short* const nb = &xb2[cur ^ 1][0];
            #pragma unroll
            for (int u = 0; u < 7; u++) {
                const int e = tid + 384 * u;
                const int i = e / 45;
                const int c = 4 * e - i * 180;
                *reinterpret_cast<unsigned*>(nb + i * 200 + c)     = pack2(nxv[u].x, nxv[u].y);
                *reinterpret_cast<unsigned*>(nb + i * 200 + c + 2) = pack2(nxv[u].z, nxv[u].w);
            }
            if (tid < 192) {
                const int e = 2688 + tid;
                const int i = e / 45;
                const int c = 4 * e - i * 180;
                *reinterpret_cast<unsigned*>(nb + i * 200 + c)     = pack2(nxt.x, nxt.y);
                *reinterpret_cast<unsigned*>(nb + i * 200 + c + 2) = pack2(nxt.z, nxt.w);
            }
        }
        __syncthreads();                         // next-x visible; xb free
        cur ^= 1;
    }
}

extern "C" void kernel_launch(void* const* d_in, const int* in_sizes, int n_in,
                              void* d_out, int out_size, void* d_ws, size_t ws_size,
                              hipStream_t stream) {
    const float* windows = (const float*)d_in[0];
    const float* mask    = (const float*)d_in[1];
    const float* wqkv    = (const float*)d_in[2];
    const float* btab    = (const float*)d_in[3];
    const float* wproj   = (const float*)d_in[4];
    const float* bproj   = (const float*)d_in[5];

    bf16*  wqkvT  = (bf16*)d_ws;
    bf16*  wprojT = (bf16*)((char*)d_ws + 221184);
    float* relb   = (float*)((char*)d_ws + 294912);

    hipLaunchKernelGGL(prep_w, dim3(672), dim3(256), 0, stream,
                       wqkv, wproj, btab, wqkvT, wprojT, relb);
    hipLaunchKernelGGL(swin_mfma, dim3(1024), dim3(384), 0, stream,
                       windows, mask, bproj, wqkvT, wprojT, relb, (float*)d_out);
}

// Round 17
// 471.441 us; speedup vs baseline: 1.3694x; 1.3694x over previous
//
#include <hip/hip_runtime.h>

// Swin window attention, fused MFMA pipeline, 3-wave blocks for occupancy.
// One block (192 thr = 3 waves) per window; wave wq owns heads {2wq, 2wq+1}
// sequentially. B=4096, N=64, C=180, H=6, D=30 (pad 32), WNum=1024.
//
// Round-17 = round-16 thesis with the overflow fixed:
//   - r16's NaN: z [64][192] bf16 = 49152 B > 46080 B window region ->
//     overran into window b+1 (cross-block race). Fix: z lives in d_ws
//     (z[4096][64][192] bf16 at +393216; r7/r8 established ws_size covers
//     this exact footprint). Runtime check falls back to the r13 6-wave
//     kernel (285.9 us champion) if ws is too small.
//   - 3-wave blocks: 16 slots/CU / 3 = 5 blocks/CU -> 5 windows in flight
//     (was 2), LDS 5 x 25.6 KB = 128 KB <= 160.
//   - z pad cols 180..191 never written: they hit wprojT's ZERO k-rows
//     (prep_w zeroes k>=180) and poison 0xAA is finite bf16 -> contributes
//     exactly 0, deterministic.
//   - same-block z write -> __syncthreads (drains vmcnt(0)) -> read: coherent
//     (same CU; L2-resident, 24 KB/window).
//
// d_ws (prep_w fills every launch):
//   [0)       wqkvT  bf16 [576][192]  oc = h*96 + sec*32 + d  (0=q,1=k,2=v)
//   [221184)  wprojT bf16 [192][192]  n-major (k>=180 rows ZERO)
//   [294912)  relb   f32  [6][64][64] pre-gathered rel-pos bias
//   [393216)  zws    bf16 [4096][64][192]  (3-wave path only)
//
// Fragment-permutation trick (verified r2-r15): MFMA contracts A-slot(g,s)
// with B-slot(g,s); q/k fragments carry d(g,s)=16*(s>=4)+4g+(s&3) and P/V
// fragments carry j(g,s,k2)=32k2+16*(s>=4)+4g+(s&3) -- identical bijections
// on both operands, so no cross-lane traffic anywhere.

typedef __bf16 bf16;
typedef bf16 bf16x8 __attribute__((ext_vector_type(8)));
typedef float f32x4 __attribute__((ext_vector_type(4)));

#define MFMA(a, b, c) __builtin_amdgcn_mfma_f32_16x16x32_bf16(a, b, c, 0, 0, 0)

__global__ void prep_w(const float* __restrict__ wqkv,
                       const float* __restrict__ wproj,
                       const float* __restrict__ btab,
                       bf16* __restrict__ wqkvT,
                       bf16* __restrict__ wprojT,
                       float* __restrict__ relb)
{
    const int idx = blockIdx.x * 256 + threadIdx.x;
    if (idx < 110592) {                          // wqkvT [576][192]
        const int oc = idx / 192, kk = idx - oc * 192;
        const int h = oc / 96, r = oc - h * 96;
        const int sec = r >> 5, d = r & 31;
        wqkvT[idx] = (bf16)((kk < 180 && d < 30) ? wqkv[kk * 540 + sec * 180 + h * 30 + d] : 0.f);
    } else if (idx < 147456) {                   // wprojT [192][192]
        const int r = idx - 110592;
        const int n = r / 192, k = r - n * 192;
        wprojT[r] = (bf16)((n < 180 && k < 180) ? wproj[k * 180 + n] : 0.f);
    } else if (idx < 172032) {                   // relb [6][64][64]
        const int r = idx - 147456;
        const int h = r >> 12;
        const int ij = r & 4095;
        const int i = ij >> 6, j = ij & 63;
        const int rel = ((i >> 3) - (j >> 3) + 7) * 15 + ((i & 7) - (j & 7) + 7);
        relb[r] = btab[rel * 6 + h];
    }
}

__device__ __forceinline__ unsigned pack2(float a, float b) {
    return (unsigned)__builtin_bit_cast(unsigned short, (bf16)a)
         | ((unsigned)__builtin_bit_cast(unsigned short, (bf16)b) << 16);
}

// ================= 3-wave path: z via d_ws =================
__global__ __launch_bounds__(192, 4)
void swin_mfma3(const float* __restrict__ xg_all,
                const float* __restrict__ mask_all,
                const float* __restrict__ bproj,
                const bf16* __restrict__ wqkvT,
                const bf16* __restrict__ wprojT,
                const float* __restrict__ relb,
                bf16* __restrict__ zws,
                float* __restrict__ outg)
{
    __shared__ __align__(16) short xb[64 * 200];   // x bf16 (z goes to d_ws)

    const int b    = blockIdx.x;
    const int tid  = threadIdx.x;                  // 0..191
    const int wq   = tid >> 6;                     // wave 0..2
    const int lane = tid & 63;
    const int l15  = lane & 15;
    const int g    = lane >> 4;                    // 0..3

    const float* xg    = xg_all + (size_t)b * 11520;
    const float* maskw = mask_all + (size_t)(b & 1023) * 4096;
    bf16* const  zw    = zws + (size_t)b * 12288;  // z [64][192] bf16

    // ---- phase 1: x -> bf16 xb. 2880 float4 = 192 thr x 15 exactly.
    {
        float4 xv[15];
        #pragma unroll
        for (int u = 0; u < 15; u++)
            xv[u] = *reinterpret_cast<const float4*>(xg + 4 * (tid + 192 * u));
        for (int e = tid; e < 640; e += 192) {     // zero pad cols [180..200)
            const int i = e / 10;
            ((unsigned*)(xb + i * 200 + 180))[e - i * 10] = 0u;
        }
        #pragma unroll
        for (int u = 0; u < 15; u++) {
            const int e = tid + 192 * u;           // float4 index
            const int i = e / 45;
            const int c = 4 * e - i * 180;
            *reinterpret_cast<unsigned*>(xb + i * 200 + c)     = pack2(xv[u].x, xv[u].y);
            *reinterpret_cast<unsigned*>(xb + i * 200 + c + 2) = pack2(xv[u].z, xv[u].w);
        }
    }
    __syncthreads();

    // ---- per-head pipeline: wave wq processes heads 2wq, 2wq+1 sequentially
    #pragma unroll 1
    for (int hh = 0; hh < 2; ++hh) {
        const int h = 2 * wq + hh;
        const bf16* wqh = wqkvT + (size_t)(h * 96) * 192;
        const float* relh = relb + h * 4096;
        const int rowoff = l15 * 192 + 8 * g;

        // ---- phase 2qk: q,k (swapped mfma: lane=token, regs=channels)
        bf16x8 qf[4], kf[4];                       // slot s <-> d = 16*(s>=4)+4g+(s&3)
        {
            f32x4 aqk[4][4];                       // [ct][tt] ct: q0,q1,k0,k1
            #pragma unroll
            for (int ct = 0; ct < 4; ct++)
                #pragma unroll
                for (int tt = 0; tt < 4; tt++) aqk[ct][tt] = (f32x4)0.f;
            #pragma unroll
            for (int ks = 0; ks < 6; ks++) {
                bf16x8 xf[4];
                #pragma unroll
                for (int tt = 0; tt < 4; tt++)
                    xf[tt] = *reinterpret_cast<const bf16x8*>(xb + (16 * tt + l15) * 200 + 32 * ks + 8 * g);
                __builtin_amdgcn_s_setprio(1);
                #pragma unroll
                for (int ct = 0; ct < 4; ct++) {
                    const bf16x8 wf = *reinterpret_cast<const bf16x8*>(wqh + ct * 3072 + rowoff + 32 * ks);
                    #pragma unroll
                    for (int tt = 0; tt < 4; tt++)
                        aqk[ct][tt] = MFMA(wf, xf[tt], aqk[ct][tt]);
                }
                __builtin_amdgcn_s_setprio(0);
            }
            #pragma unroll
            for (int tt = 0; tt < 4; tt++)
                #pragma unroll
                for (int s = 0; s < 8; s++) {
                    qf[tt][s] = (bf16)(aqk[s >> 2][tt][s & 3] * 0.18257418583505537f);
                    kf[tt][s] = (bf16)(aqk[2 + (s >> 2)][tt][s & 3]);
                }
        }
        __builtin_amdgcn_sched_barrier(0);

        // ---- phase 3: QK^T + softmax. Bias rides the MFMA C-operand;
        // no-max softmax (validated r12/r13); it+1 bias prefetched.
        bf16x8 pf[4][2];                           // [it][k2]
        {
            f32x4 bc[4];
            {
                const float* rbb = relh + l15 * 64 + 4 * g;
                const float* mkb = maskw + l15 * 64 + 4 * g;
                #pragma unroll
                for (int jt = 0; jt < 4; jt++) {
                    const float4 rb = *reinterpret_cast<const float4*>(rbb + 16 * jt);
                    const float4 mk = *reinterpret_cast<const float4*>(mkb + 16 * jt);
                    bc[jt][0] = rb.x + mk.x; bc[jt][1] = rb.y + mk.y;
                    bc[jt][2] = rb.z + mk.z; bc[jt][3] = rb.w + mk.w;
                }
            }
            #pragma unroll
            for (int it = 0; it < 4; it++) {
                f32x4 stj[4];                      // j = 16jt+4g+r, i = 16it+l15
                __builtin_amdgcn_s_setprio(1);
                #pragma unroll
                for (int jt = 0; jt < 4; jt++) stj[jt] = MFMA(kf[jt], qf[it], bc[jt]);
                __builtin_amdgcn_s_setprio(0);

                f32x4 bn[4];
                if (it < 3) {
                    const int i1 = 16 * (it + 1) + l15;
                    const float* rbb = relh + i1 * 64 + 4 * g;
                    const float* mkb = maskw + i1 * 64 + 4 * g;
                    #pragma unroll
                    for (int jt = 0; jt < 4; jt++) {
                        const float4 rb = *reinterpret_cast<const float4*>(rbb + 16 * jt);
                        const float4 mk = *reinterpret_cast<const float4*>(mkb + 16 * jt);
                        bn[jt][0] = rb.x + mk.x; bn[jt][1] = rb.y + mk.y;
                        bn[jt][2] = rb.z + mk.z; bn[jt][3] = rb.w + mk.w;
                    }
                }

                float sum = 0.f;                   // no-max: exp directly
                #pragma unroll
                for (int jt = 0; jt < 4; jt++) {
                    const float e0 = __expf(stj[jt][0]);
                    const float e1 = __expf(stj[jt][1]);
                    const float e2 = __expf(stj[jt][2]);
                    const float e3 = __expf(stj[jt][3]);
                    stj[jt][0] = e0; stj[jt][1] = e1; stj[jt][2] = e2; stj[jt][3] = e3;
                    sum += (e0 + e1) + (e2 + e3);
                }
                sum += __shfl_xor(sum, 16);
                sum += __shfl_xor(sum, 32);
                const float inv = 1.0f / sum;
                #pragma unroll
                for (int k2 = 0; k2 < 2; k2++)
                    #pragma unroll
                    for (int s = 0; s < 8; s++)
                        pf[it][k2][s] = (bf16)(stj[2 * k2 + (s >> 2)][s & 3] * inv);

                if (it < 3) {
                    #pragma unroll
                    for (int jt = 0; jt < 4; jt++) bc[jt] = bn[jt];
                }
            }
        }
        __builtin_amdgcn_sched_barrier(0);

        // ---- phase 2v: v (normal mfma: lane=channel, regs=tokens)
        bf16x8 vf[2][2];                           // [cv][k2]
        {
            f32x4 av[4][2];                        // [tt][cv]
            #pragma unroll
            for (int tt = 0; tt < 4; tt++) { av[tt][0] = (f32x4)0.f; av[tt][1] = (f32x4)0.f; }
            #pragma unroll
            for (int ks = 0; ks < 6; ks++) {
                bf16x8 xf[4];
                #pragma unroll
                for (int tt = 0; tt < 4; tt++)
                    xf[tt] = *reinterpret_cast<const bf16x8*>(xb + (16 * tt + l15) * 200 + 32 * ks + 8 * g);
                __builtin_amdgcn_s_setprio(1);
                #pragma unroll
                for (int cv = 0; cv < 2; cv++) {
                    const bf16x8 wf = *reinterpret_cast<const bf16x8*>(wqh + (4 + cv) * 3072 + rowoff + 32 * ks);
                    #pragma unroll
                    for (int tt = 0; tt < 4; tt++)
                        av[tt][cv] = MFMA(xf[tt], wf, av[tt][cv]);
                }
                __builtin_amdgcn_s_setprio(0);
            }
            #pragma unroll
            for (int cv = 0; cv < 2; cv++)
                #pragma unroll
                for (int k2 = 0; k2 < 2; k2++)
                    #pragma unroll
                    for (int s = 0; s < 8; s++)
                        vf[cv][k2][s] = (bf16)(av[2 * k2 + (s >> 2)][cv][s & 3]);
        }
        __builtin_amdgcn_sched_barrier(0);

        // ---- phase 4: PV in registers; z -> zws [64][192] bf16
        f32x4 zacc[4][2];                          // [it][cv]: z[16it+4g+r][16cv+l15]
        #pragma unroll
        for (int it = 0; it < 4; it++) { zacc[it][0] = (f32x4)0.f; zacc[it][1] = (f32x4)0.f; }
        __builtin_amdgcn_s_setprio(1);
        #pragma unroll
        for (int k2 = 0; k2 < 2; k2++)
            #pragma unroll
            for (int cv = 0; cv < 2; cv++)
                #pragma unroll
                for (int it = 0; it < 4; it++)
                    zacc[it][cv] = MFMA(pf[it][k2], vf[cv][k2], zacc[it][cv]);
        __builtin_amdgcn_s_setprio(0);

        #pragma unroll
        for (int cv = 0; cv < 2; cv++) {
            const int d = 16 * cv + l15;
            if (d < 30) {
                #pragma unroll
                for (int it = 0; it < 4; it++)
                    #pragma unroll
                    for (int r = 0; r < 4; r++)
                        zw[(16 * it + 4 * g + r) * 192 + h * 30 + d] = (bf16)zacc[it][cv][r];
            }
        }
        __builtin_amdgcn_sched_barrier(0);
    }
    __syncthreads();                               // drains vmcnt(0): all z visible

    // ---- phase 5: proj GEMM + bias -> out. Wave wq owns ntiles 4wq..4wq+3.
    // z fragments read from zws (L2-hot: this block just wrote them; cols
    // 180..191 unwritten but hit wprojT's zero k-rows -> contribute 0).
    {
        f32x4 pa[4][4];                            // [mt][q3]
        #pragma unroll
        for (int mt = 0; mt < 4; mt++)
            #pragma unroll
            for (int q3 = 0; q3 < 4; q3++) pa[mt][q3] = (f32x4)0.f;
        #pragma unroll
        for (int ks = 0; ks < 6; ks++) {
            bf16x8 zf[4];
            #pragma unroll
            for (int mt = 0; mt < 4; mt++)
                zf[mt] = *reinterpret_cast<const bf16x8*>(zw + (16 * mt + l15) * 192 + 32 * ks + 8 * g);
            __builtin_amdgcn_s_setprio(1);
            #pragma unroll
            for (int q3 = 0; q3 < 4; q3++) {
                const int nt = 4 * wq + q3;
                const bf16x8 wf = *reinterpret_cast<const bf16x8*>(
                    wprojT + (nt * 16 + l15) * 192 + 32 * ks + 8 * g);
                #pragma unroll
                for (int mt = 0; mt < 4; mt++)
                    pa[mt][q3] = MFMA(zf[mt], wf, pa[mt][q3]);
            }
            __builtin_amdgcn_s_setprio(0);
        }
        #pragma unroll
        for (int q3 = 0; q3 < 4; q3++) {
            const int n = (4 * wq + q3) * 16 + l15;
            if (n < 180) {
                const float bn = bproj[n];
                float* const ob = outg + (size_t)b * 11520 + n;
                #pragma unroll
                for (int mt = 0; mt < 4; mt++)
                    #pragma unroll
                    for (int r = 0; r < 4; r++)
                        ob[(16 * mt + 4 * g + r) * 180] = pa[mt][q3][r] + bn;
            }
        }
    }
}

// ================= 6-wave fallback: verbatim r13 (285.9 us) =================
__global__ __launch_bounds__(384, 4)
void swin_mfma6(const float* __restrict__ xg_all,
                const float* __restrict__ mask_all,
                const float* __restrict__ bproj,
                const bf16* __restrict__ wqkvT,
                const bf16* __restrict__ wprojT,
                const float* __restrict__ relb,
                float* __restrict__ outg)
{
    __shared__ __align__(16) short xb[64 * 200];

    const int b    = blockIdx.x;
    const int tid  = threadIdx.x;
    const int w    = tid >> 6;
    const int lane = tid & 63;
    const int l15  = lane & 15;
    const int g    = lane >> 4;

    const float* xg    = xg_all + (size_t)b * 11520;
    const float* maskw = mask_all + (size_t)(b & 1023) * 4096;

    {
        float4 xv[7];
        #pragma unroll
        for (int u = 0; u < 7; u++)
            xv[u] = *reinterpret_cast<const float4*>(xg + 4 * (tid + 384 * u));
        float4 xt;
        if (tid < 192) xt = *reinterpret_cast<const float4*>(xg + 4 * (2688 + tid));
        for (int e = tid; e < 640; e += 384) {
            const int i = e / 10;
            ((unsigned*)(xb + i * 200 + 180))[e - i * 10] = 0u;
        }
        #pragma unroll
        for (int u = 0; u < 7; u++) {
            const int e = tid + 384 * u;
            const int i = e / 45;
            const int c = 4 * e - i * 180;
            *reinterpret_cast<unsigned*>(xb + i * 200 + c)     = pack2(xv[u].x, xv[u].y);
            *reinterpret_cast<unsigned*>(xb + i * 200 + c + 2) = pack2(xv[u].z, xv[u].w);
        }
        if (tid < 192) {
            const int e = 2688 + tid;
            const int i = e / 45;
            const int c = 4 * e - i * 180;
            *reinterpret_cast<unsigned*>(xb + i * 200 + c)     = pack2(xt.x, xt.y);
            *reinterpret_cast<unsigned*>(xb + i * 200 + c + 2) = pack2(xt.z, xt.w);
        }
    }
    __syncthreads();

    const bf16* wqh = wqkvT + (size_t)(w * 96) * 192;
    const int rowoff = l15 * 192 + 8 * g;

    bf16x8 qf[4], kf[4];
    {
        f32x4 aqk[4][4];
        #pragma unroll
        for (int ct = 0; ct < 4; ct++)
            #pragma unroll
            for (int tt = 0; tt < 4; tt++) aqk[ct][tt] = (f32x4)0.f;
        #pragma unroll
        for (int ks = 0; ks < 6; ks++) {
            bf16x8 xf[4];
            #pragma unroll
            for (int tt = 0; tt < 4; tt++)
                xf[tt] = *reinterpret_cast<const bf16x8*>(xb + (16 * tt + l15) * 200 + 32 * ks + 8 * g);
            __builtin_amdgcn_s_setprio(1);
            #pragma unroll
            for (int ct = 0; ct < 4; ct++) {
                const bf16x8 wf = *reinterpret_cast<const bf16x8*>(wqh + ct * 3072 + rowoff + 32 * ks);
                #pragma unroll
                for (int tt = 0; tt < 4; tt++)
                    aqk[ct][tt] = MFMA(wf, xf[tt], aqk[ct][tt]);
            }
            __builtin_amdgcn_s_setprio(0);
        }
        #pragma unroll
        for (int tt = 0; tt < 4; tt++)
            #pragma unroll
            for (int s = 0; s < 8; s++) {
                qf[tt][s] = (bf16)(aqk[s >> 2][tt][s & 3] * 0.18257418583505537f);
                kf[tt][s] = (bf16)(aqk[2 + (s >> 2)][tt][s & 3]);
            }
    }
    __builtin_amdgcn_sched_barrier(0);

    bf16x8 pf[4][2];
    {
        const float* relh = relb + w * 4096;
        f32x4 bc[4];
        {
            const float* rbb = relh + l15 * 64 + 4 * g;
            const float* mkb = maskw + l15 * 64 + 4 * g;
            #pragma unroll
            for (int jt = 0; jt < 4; jt++) {
                const float4 rb = *reinterpret_cast<const float4*>(rbb + 16 * jt);
                const float4 mk = *reinterpret_cast<const float4*>(mkb + 16 * jt);
                bc[jt][0] = rb.x + mk.x; bc[jt][1] = rb.y + mk.y;
                bc[jt][2] = rb.z + mk.z; bc[jt][3] = rb.w + mk.w;
            }
        }
        #pragma unroll
        for (int it = 0; it < 4; it++) {
            f32x4 stj[4];
            __builtin_amdgcn_s_setprio(1);
            #pragma unroll
            for (int jt = 0; jt < 4; jt++) stj[jt] = MFMA(kf[jt], qf[it], bc[jt]);
            __builtin_amdgcn_s_setprio(0);

            f32x4 bn[4];
            if (it < 3) {
                const int i1 = 16 * (it + 1) + l15;
                const float* rbb = relh + i1 * 64 + 4 * g;
                const float* mkb = maskw + i1 * 64 + 4 * g;
                #pragma unroll
                for (int jt = 0; jt < 4; jt++) {
                    const float4 rb = *reinterpret_cast<const float4*>(rbb + 16 * jt);
                    const float4 mk = *reinterpret_cast<const float4*>(mkb + 16 * jt);
                    bn[jt][0] = rb.x + mk.x; bn[jt][1] = rb.y + mk.y;
                    bn[jt][2] = rb.z + mk.z; bn[jt][3] = rb.w + mk.w;
                }
            }

            float sum = 0.f;
            #pragma unroll
            for (int jt = 0; jt < 4; jt++) {
                const float e0 = __expf(stj[jt][0]);
                const float e1 = __expf(stj[jt][1]);
                const float e2 = __expf(stj[jt][2]);
                const float e3 = __expf(stj[jt][3]);
                stj[jt][0] = e0; stj[jt][1] = e1; stj[jt][2] = e2; stj[jt][3] = e3;
                sum += (e0 + e1) + (e2 + e3);
            }
            sum += __shfl_xor(sum, 16);
            sum += __shfl_xor(sum, 32);
            const float inv = 1.0f / sum;
            #pragma unroll
            for (int k2 = 0; k2 < 2; k2++)
                #pragma unroll
                for (int s = 0; s < 8; s++)
                    pf[it][k2][s] = (bf16)(stj[2 * k2 + (s >> 2)][s & 3] * inv);

            if (it < 3) {
                #pragma unroll
                for (int jt = 0; jt < 4; jt++) bc[jt] = bn[jt];
            }
        }
    }
    __builtin_amdgcn_sched_barrier(0);

    bf16x8 vf[2][2];
    {
        f32x4 av[4][2];
        #pragma unroll
        for (int tt = 0; tt < 4; tt++) { av[tt][0] = (f32x4)0.f; av[tt][1] = (f32x4)0.f; }
        #pragma unroll
        for (int ks = 0; ks < 6; ks++) {
            bf16x8 xf[4];
            #pragma unroll
            for (int tt = 0; tt < 4; tt++)
                xf[tt] = *reinterpret_cast<const bf16x8*>(xb + (16 * tt + l15) * 200 + 32 * ks + 8 * g);
            __builtin_amdgcn_s_setprio(1);
            #pragma unroll
            for (int cv = 0; cv < 2; cv++) {
                const bf16x8 wf = *reinterpret_cast<const bf16x8*>(wqh + (4 + cv) * 3072 + rowoff + 32 * ks);
                #pragma unroll
                for (int tt = 0; tt < 4; tt++)
                    av[tt][cv] = MFMA(xf[tt], wf, av[tt][cv]);
            }
            __builtin_amdgcn_s_setprio(0);
        }
        #pragma unroll
        for (int cv = 0; cv < 2; cv++)
            #pragma unroll
            for (int k2 = 0; k2 < 2; k2++)
                #pragma unroll
                for (int s = 0; s < 8; s++)
                    vf[cv][k2][s] = (bf16)(av[2 * k2 + (s >> 2)][cv][s & 3]);
    }
    __builtin_amdgcn_sched_barrier(0);

    f32x4 zacc[4][2];
    #pragma unroll
    for (int it = 0; it < 4; it++) { zacc[it][0] = (f32x4)0.f; zacc[it][1] = (f32x4)0.f; }
    __builtin_amdgcn_s_setprio(1);
    #pragma unroll
    for (int k2 = 0; k2 < 2; k2++)
        #pragma unroll
        for (int cv = 0; cv < 2; cv++)
            #pragma unroll
            for (int it = 0; it < 4; it++)
                zacc[it][cv] = MFMA(pf[it][k2], vf[cv][k2], zacc[it][cv]);
    __builtin_amdgcn_s_setprio(0);

    __syncthreads();
    #pragma unroll
    for (int cv = 0; cv < 2; cv++) {
        const int d = 16 * cv + l15;
        if (d < 30) {
            #pragma unroll
            for (int it = 0; it < 4; it++)
                #pragma unroll
                for (int r = 0; r < 4; r++)
                    xb[(16 * it + 4 * g + r) * 200 + w * 30 + d] =
                        __builtin_bit_cast(short, (bf16)zacc[it][cv][r]);
        }
    }
    __syncthreads();

    f32x4 pa[4][2];
    #pragma unroll
    for (int mt = 0; mt < 4; mt++) { pa[mt][0] = (f32x4)0.f; pa[mt][1] = (f32x4)0.f; }
    #pragma unroll
    for (int ks = 0; ks < 6; ks++) {
        bf16x8 zf[4];
        #pragma unroll
        for (int mt = 0; mt < 4; mt++)
            zf[mt] = *reinterpret_cast<const bf16x8*>(xb + (16 * mt + l15) * 200 + 32 * ks + 8 * g);
        __builtin_amdgcn_s_setprio(1);
        #pragma unroll
        for (int q2 = 0; q2 < 2; q2++) {
            const bf16x8 wf = *reinterpret_cast<const bf16x8*>(
                wprojT + ((2 * w + q2) * 16 + l15) * 192 + 32 * ks + 8 * g);
            #pragma unroll
            for (int mt = 0; mt < 4; mt++)
                pa[mt][q2] = MFMA(zf[mt], wf, pa[mt][q2]);
        }
        __builtin_amdgcn_s_setprio(0);
    }
    #pragma unroll
    for (int q2 = 0; q2 < 2; q2++) {
        const int n = (2 * w + q2) * 16 + l15;
        if (n < 180) {
            const float bn = bproj[n];
            float* const ob = outg + (size_t)b * 11520 + n;
            #pragma unroll
            for (int mt = 0; mt < 4; mt++)
                #pragma unroll
                for (int r = 0; r < 4; r++)
                    ob[(16 * mt + 4 * g + r) * 180] = pa[mt][q2][r] + bn;
        }
    }
}

extern "C" void kernel_launch(void* const* d_in, const int* in_sizes, int n_in,
                              void* d_out, int out_size, void* d_ws, size_t ws_size,
                              hipStream_t stream) {
    const float* windows = (const float*)d_in[0];
    const float* mask    = (const float*)d_in[1];
    const float* wqkv    = (const float*)d_in[2];
    const float* btab    = (const float*)d_in[3];
    const float* wproj   = (const float*)d_in[4];
    const float* bproj   = (const float*)d_in[5];

    bf16*  wqkvT  = (bf16*)d_ws;
    bf16*  wprojT = (bf16*)((char*)d_ws + 221184);
    float* relb   = (float*)((char*)d_ws + 294912);
    bf16*  zws    = (bf16*)((char*)d_ws + 393216);  // [4096][64][192] bf16

    const bool ws_ok = ws_size >= (size_t)393216 + (size_t)4096 * 12288 * 2;

    hipLaunchKernelGGL(prep_w, dim3(672), dim3(256), 0, stream,
                       wqkv, wproj, btab, wqkvT, wprojT, relb);
    if (ws_ok) {
        hipLaunchKernelGGL(swin_mfma3, dim3(4096), dim3(192), 0, stream,
                           windows, mask, bproj, wqkvT, wprojT, relb, zws, (float*)d_out);
    } else {
        hipLaunchKernelGGL(swin_mfma6, dim3(4096), dim3(384), 0, stream,
                           windows, mask, bproj, wqkvT, wprojT, relb, (float*)d_out);
    }
}

// Round 18
// 282.308 us; speedup vs baseline: 2.2868x; 1.6700x over previous
//
#include <hip/hip_runtime.h>

// Swin window attention, fused register-resident MFMA pipeline. 1 block
// (6 waves) per window; wave w owns head w. B=4096, N=64, C=180, H=6, D=30.
//
// Round-18 = round-13 (285.9 us champion) + chain-shortening reorder:
//   - v-pass moved BEFORE softmax (independent of q/k),
//   - PV fused INTO the softmax it-loop: as soon as pf[it] is packed its
//     4 PV MFMAs issue, overlapping the next it's QKT/exp VALU work
//     (separate MFMA/VALU pipes). Deletes the standalone PV phase + fence.
//   - pf no longer persists across its (8 regs live, was 32): peak ~120<=128.
//   - bias back to VALU add (r13 proved VALU non-critical), loads issued
//     before the QKT MFMA cluster so they hide under it.
//   r17 3-wave/global-z: dead (RMW write amplification, 471us).
//
// d_ws (prep_w fills every launch):
//   [0)       wqkvT  bf16 [576][192]  oc = h*96 + sec*32 + d  (0=q,1=k,2=v)
//   [221184)  wprojT bf16 [192][192]  n-major
//   [294912)  relb   f32  [6][64][64] pre-gathered rel-pos bias
//
// LDS: one [64][200] short buffer (x bf16, later z bf16). 25.6 KB.
//
// Fragment-permutation trick (verified r2-r17): MFMA contracts A-slot(g,s)
// with B-slot(g,s); q/k fragments carry d(g,s)=16*(s>=4)+4g+(s&3) and P/V
// fragments carry j(g,s,k2)=32k2+16*(s>=4)+4g+(s&3) -- identical bijections
// on both operands, so no cross-lane traffic anywhere.

typedef __bf16 bf16;
typedef bf16 bf16x8 __attribute__((ext_vector_type(8)));
typedef float f32x4 __attribute__((ext_vector_type(4)));

#define MFMA(a, b, c) __builtin_amdgcn_mfma_f32_16x16x32_bf16(a, b, c, 0, 0, 0)

__global__ void prep_w(const float* __restrict__ wqkv,
                       const float* __restrict__ wproj,
                       const float* __restrict__ btab,
                       bf16* __restrict__ wqkvT,
                       bf16* __restrict__ wprojT,
                       float* __restrict__ relb)
{
    const int idx = blockIdx.x * 256 + threadIdx.x;
    if (idx < 110592) {                          // wqkvT [576][192]
        const int oc = idx / 192, kk = idx - oc * 192;
        const int h = oc / 96, r = oc - h * 96;
        const int sec = r >> 5, d = r & 31;
        wqkvT[idx] = (bf16)((kk < 180 && d < 30) ? wqkv[kk * 540 + sec * 180 + h * 30 + d] : 0.f);
    } else if (idx < 147456) {                   // wprojT [192][192]
        const int r = idx - 110592;
        const int n = r / 192, k = r - n * 192;
        wprojT[r] = (bf16)((n < 180 && k < 180) ? wproj[k * 180 + n] : 0.f);
    } else if (idx < 172032) {                   // relb [6][64][64]
        const int r = idx - 147456;
        const int h = r >> 12;
        const int ij = r & 4095;
        const int i = ij >> 6, j = ij & 63;
        const int rel = ((i >> 3) - (j >> 3) + 7) * 15 + ((i & 7) - (j & 7) + 7);
        relb[r] = btab[rel * 6 + h];
    }
}

__device__ __forceinline__ unsigned pack2(float a, float b) {
    return (unsigned)__builtin_bit_cast(unsigned short, (bf16)a)
         | ((unsigned)__builtin_bit_cast(unsigned short, (bf16)b) << 16);
}

__global__ __launch_bounds__(384, 4)
void swin_mfma(const float* __restrict__ xg_all,
               const float* __restrict__ mask_all,
               const float* __restrict__ bproj,
               const bf16* __restrict__ wqkvT,
               const bf16* __restrict__ wprojT,
               const float* __restrict__ relb,
               float* __restrict__ outg)
{
    __shared__ __align__(16) short xb[64 * 200];   // x bf16, later z bf16

    const int b    = blockIdx.x;
    const int tid  = threadIdx.x;
    const int w    = tid >> 6;                     // wave = head, 0..5
    const int lane = tid & 63;
    const int l15  = lane & 15;
    const int g    = lane >> 4;                    // 0..3

    const float* xg    = xg_all + (size_t)b * 11520;
    const float* maskw = mask_all + (size_t)(b & 1023) * 4096;

    // ---- phase 1: x -> bf16 xb. Batch loads (7-8 float4/thread), then cvt.
    {
        float4 xv[7];
        #pragma unroll
        for (int u = 0; u < 7; u++)
            xv[u] = *reinterpret_cast<const float4*>(xg + 4 * (tid + 384 * u));
        float4 xt;
        if (tid < 192) xt = *reinterpret_cast<const float4*>(xg + 4 * (2688 + tid));
        for (int e = tid; e < 640; e += 384) {     // zero pad cols [180..200)
            const int i = e / 10;
            ((unsigned*)(xb + i * 200 + 180))[e - i * 10] = 0u;
        }
        #pragma unroll
        for (int u = 0; u < 7; u++) {
            const int e = tid + 384 * u;           // float4 index
            const int i = e / 45;
            const int c = 4 * e - i * 180;
            *reinterpret_cast<unsigned*>(xb + i * 200 + c)     = pack2(xv[u].x, xv[u].y);
            *reinterpret_cast<unsigned*>(xb + i * 200 + c + 2) = pack2(xv[u].z, xv[u].w);
        }
        if (tid < 192) {
            const int e = 2688 + tid;
            const int i = e / 45;
            const int c = 4 * e - i * 180;
            *reinterpret_cast<unsigned*>(xb + i * 200 + c)     = pack2(xt.x, xt.y);
            *reinterpret_cast<unsigned*>(xb + i * 200 + c + 2) = pack2(xt.z, xt.w);
        }
    }
    __syncthreads();

    const bf16* wqh = wqkvT + (size_t)(w * 96) * 192;
    const int rowoff = l15 * 192 + 8 * g;

    // ---- phase 2qk: q,k for head w (swapped mfma: lane=token, regs=channels)
    bf16x8 qf[4], kf[4];                           // slot s <-> d = 16*(s>=4)+4g+(s&3)
    {
        f32x4 aqk[4][4];                           // [ct][tt] ct: q0,q1,k0,k1
        #pragma unroll
        for (int ct = 0; ct < 4; ct++)
            #pragma unroll
            for (int tt = 0; tt < 4; tt++) aqk[ct][tt] = (f32x4)0.f;
        #pragma unroll
        for (int ks = 0; ks < 6; ks++) {
            bf16x8 xf[4];
            #pragma unroll
            for (int tt = 0; tt < 4; tt++)
                xf[tt] = *reinterpret_cast<const bf16x8*>(xb + (16 * tt + l15) * 200 + 32 * ks + 8 * g);
            __builtin_amdgcn_s_setprio(1);
            #pragma unroll
            for (int ct = 0; ct < 4; ct++) {
                const bf16x8 wf = *reinterpret_cast<const bf16x8*>(wqh + ct * 3072 + rowoff + 32 * ks);
                #pragma unroll
                for (int tt = 0; tt < 4; tt++)
                    aqk[ct][tt] = MFMA(wf, xf[tt], aqk[ct][tt]);
            }
            __builtin_amdgcn_s_setprio(0);
        }
        #pragma unroll
        for (int tt = 0; tt < 4; tt++)
            #pragma unroll
            for (int s = 0; s < 8; s++) {
                qf[tt][s] = (bf16)(aqk[s >> 2][tt][s & 3] * 0.18257418583505537f);
                kf[tt][s] = (bf16)(aqk[2 + (s >> 2)][tt][s & 3]);
            }
    }
    __builtin_amdgcn_sched_barrier(0);

    // ---- phase 2v (moved BEFORE softmax): v (normal mfma: lane=channel,
    // regs=tokens). qf/kf (32 regs) stay live: peak here ~80+32 = fine.
    bf16x8 vf[2][2];                               // [cv][k2]
    {
        f32x4 av[4][2];                            // [tt][cv]
        #pragma unroll
        for (int tt = 0; tt < 4; tt++) { av[tt][0] = (f32x4)0.f; av[tt][1] = (f32x4)0.f; }
        #pragma unroll
        for (int ks = 0; ks < 6; ks++) {
            bf16x8 xf[4];
            #pragma unroll
            for (int tt = 0; tt < 4; tt++)
                xf[tt] = *reinterpret_cast<const bf16x8*>(xb + (16 * tt + l15) * 200 + 32 * ks + 8 * g);
            __builtin_amdgcn_s_setprio(1);
            #pragma unroll
            for (int cv = 0; cv < 2; cv++) {
                const bf16x8 wf = *reinterpret_cast<const bf16x8*>(wqh + (4 + cv) * 3072 + rowoff + 32 * ks);
                #pragma unroll
                for (int tt = 0; tt < 4; tt++)
                    av[tt][cv] = MFMA(xf[tt], wf, av[tt][cv]);
            }
            __builtin_amdgcn_s_setprio(0);
        }
        #pragma unroll
        for (int cv = 0; cv < 2; cv++)
            #pragma unroll
            for (int k2 = 0; k2 < 2; k2++)
                #pragma unroll
                for (int s = 0; s < 8; s++)
                    vf[cv][k2][s] = (bf16)(av[2 * k2 + (s >> 2)][cv][s & 3]);
    }
    __builtin_amdgcn_sched_barrier(0);

    // ---- phase 3+4 fused: QK^T + softmax + PV per it. pf[it]'s PV MFMAs
    // issue immediately after packing and overlap the next it's QKT/exp.
    f32x4 zacc[4][2];                              // [it][cv]: z[16it+4g+r][16cv+l15]
    #pragma unroll
    for (int it = 0; it < 4; it++) { zacc[it][0] = (f32x4)0.f; zacc[it][1] = (f32x4)0.f; }
    {
        const float* relh = relb + w * 4096;
        #pragma unroll
        for (int it = 0; it < 4; it++) {
            // issue bias loads first: they complete under the QKT MFMAs
            const int i = 16 * it + l15;
            const float* rbb = relh + i * 64 + 4 * g;
            const float* mkb = maskw + i * 64 + 4 * g;
            float4 rb[4], mk[4];
            #pragma unroll
            for (int jt = 0; jt < 4; jt++) {
                rb[jt] = *reinterpret_cast<const float4*>(rbb + 16 * jt);
                mk[jt] = *reinterpret_cast<const float4*>(mkb + 16 * jt);
            }

            f32x4 stj[4];                          // j = 16jt+4g+r
            __builtin_amdgcn_s_setprio(1);
            #pragma unroll
            for (int jt = 0; jt < 4; jt++) stj[jt] = MFMA(kf[jt], qf[it], (f32x4)0.f);
            __builtin_amdgcn_s_setprio(0);

            float sum = 0.f;                       // no-max softmax (r12/r13)
            #pragma unroll
            for (int jt = 0; jt < 4; jt++) {
                const float e0 = __expf(stj[jt][0] + rb[jt].x + mk[jt].x);
                const float e1 = __expf(stj[jt][1] + rb[jt].y + mk[jt].y);
                const float e2 = __expf(stj[jt][2] + rb[jt].z + mk[jt].z);
                const float e3 = __expf(stj[jt][3] + rb[jt].w + mk[jt].w);
                stj[jt][0] = e0; stj[jt][1] = e1; stj[jt][2] = e2; stj[jt][3] = e3;
                sum += (e0 + e1) + (e2 + e3);
            }
            sum += __shfl_xor(sum, 16);
            sum += __shfl_xor(sum, 32);
            const float inv = 1.0f / sum;

            bf16x8 pfc[2];                         // this it's P fragments only
            #pragma unroll
            for (int k2 = 0; k2 < 2; k2++)
                #pragma unroll
                for (int s = 0; s < 8; s++)
                    pfc[k2][s] = (bf16)(stj[2 * k2 + (s >> 2)][s & 3] * inv);

            // PV for this it: 4 MFMAs, overlap next it's VALU work
            __builtin_amdgcn_s_setprio(1);
            #pragma unroll
            for (int k2 = 0; k2 < 2; k2++)
                #pragma unroll
                for (int cv = 0; cv < 2; cv++)
                    zacc[it][cv] = MFMA(pfc[k2], vf[cv][k2], zacc[it][cv]);
            __builtin_amdgcn_s_setprio(0);
        }
    }

    __syncthreads();                               // all waves done reading xb
    // z -> zb (aliases xb; pad cols [180..200) still zero from phase 1)
    #pragma unroll
    for (int cv = 0; cv < 2; cv++) {
        const int d = 16 * cv + l15;
        if (d < 30) {
            #pragma unroll
            for (int it = 0; it < 4; it++)
                #pragma unroll
                for (int r = 0; r < 4; r++)
                    xb[(16 * it + 4 * g + r) * 200 + w * 30 + d] =
                        __builtin_bit_cast(short, (bf16)zacc[it][cv][r]);
        }
    }
    __syncthreads();

    // ---- phase 5: proj GEMM + bias -> out
    f32x4 pa[4][2];
    #pragma unroll
    for (int mt = 0; mt < 4; mt++) { pa[mt][0] = (f32x4)0.f; pa[mt][1] = (f32x4)0.f; }
    #pragma unroll
    for (int ks = 0; ks < 6; ks++) {
        bf16x8 zf[4];
        #pragma unroll
        for (int mt = 0; mt < 4; mt++)
            zf[mt] = *reinterpret_cast<const bf16x8*>(xb + (16 * mt + l15) * 200 + 32 * ks + 8 * g);
        __builtin_amdgcn_s_setprio(1);
        #pragma unroll
        for (int q2 = 0; q2 < 2; q2++) {
            const bf16x8 wf = *reinterpret_cast<const bf16x8*>(
                wprojT + ((2 * w + q2) * 16 + l15) * 192 + 32 * ks + 8 * g);
            #pragma unroll
            for (int mt = 0; mt < 4; mt++)
                pa[mt][q2] = MFMA(zf[mt], wf, pa[mt][q2]);
        }
        __builtin_amdgcn_s_setprio(0);
    }
    #pragma unroll
    for (int q2 = 0; q2 < 2; q2++) {
        const int n = (2 * w + q2) * 16 + l15;
        if (n < 180) {
            const float bn = bproj[n];
            float* const ob = outg + (size_t)b * 11520 + n;
            #pragma unroll
            for (int mt = 0; mt < 4; mt++)
                #pragma unroll
                for (int r = 0; r < 4; r++)
                    ob[(16 * mt + 4 * g + r) * 180] = pa[mt][q2][r] + bn;
        }
    }
}

extern "C" void kernel_launch(void* const* d_in, const int* in_sizes, int n_in,
                              void* d_out, int out_size, void* d_ws, size_t ws_size,
                              hipStream_t stream) {
    const float* windows = (const float*)d_in[0];
    const float* mask    = (const float*)d_in[1];
    const float* wqkv    = (const float*)d_in[2];
    const float* btab    = (const float*)d_in[3];
    const float* wproj   = (const float*)d_in[4];
    const float* bproj   = (const float*)d_in[5];

    bf16*  wqkvT  = (bf16*)d_ws;
    bf16*  wprojT = (bf16*)((char*)d_ws + 221184);
    float* relb   = (float*)((char*)d_ws + 294912);

    hipLaunchKernelGGL(prep_w, dim3(672), dim3(256), 0, stream,
                       wqkv, wproj, btab, wqkvT, wprojT, relb);
    hipLaunchKernelGGL(swin_mfma, dim3(4096), dim3(384), 0, stream,
                       windows, mask, bproj, wqkvT, wprojT, relb, (float*)d_out);
}